// Round 1
// baseline (4600.967 us; speedup 1.0000x reference)
//
#include <hip/hip_runtime.h>
#include <hip/hip_bf16.h>
#include <cstdint>
#include <cstddef>

// ---------------------------------------------------------------------------
// 2-layer GRU decoder. B=8192, H=512, ENC=1024, ATOM=64, 49 steps.
// 3 kernels/step: gru0_step (LDS GEMM + gate), gru1_fused (merged dual GEMM
// in ONE K-loop), out_mfma (BM=32, 256 blocks, double-buffered prefetch).
// Gate-permuted weights: q = 48*(j/16) + 16*g + (j%16) <-> orig row g*512+j,
// so a 48-col wave strip holds gates r,z,n for 16 h-units at matching lanes.
// Grid dim3(128,8): m-tile fastest-varying => consecutive blocks round-robin
// across XCDs get consecutive m-tiles of ONE strip; each XCD only reads
// m-tiles === xcd (mod 8)  (R4 post-mortem: wrong order => 8x HBM fetch).
// R-this: (a) gru1's two sequential 16-iter K-loops merged into one loop
// (barriers 64->32, 24 MFMA + 8 loads per phase); (b) out_mfma BM 64->32
// (grid 128->256, all CUs active) + 2-phase double-buffer so the serial
// load->compute chain overlaps (K3 had 1 block/CU => no implicit TLP).
// ---------------------------------------------------------------------------

typedef __attribute__((ext_vector_type(8))) __bf16 bf16x8;
typedef __attribute__((ext_vector_type(4))) __bf16 bf16x4;
typedef __attribute__((ext_vector_type(4))) float f32x4;

#define B_ROWS 8192
#define HID 512
#define GATE3 1536
#define ATOM 64
#define NSTEP 49

#define GLOAD_LDS16(gp, sp)                                                   \
  __builtin_amdgcn_global_load_lds(                                           \
      (__attribute__((address_space(1))) void*)(gp),                          \
      (__attribute__((address_space(3))) void*)(sp), 16, 0, 0)

__device__ inline float sig_(float x) { return 1.f / (1.f + __expf(-x)); }
__device__ inline float tanh_(float x) { return 2.f / (1.f + __expf(-2.f * x)) - 1.f; }

// ---------------------------------------------------------------------------
// Core tile GEMM: acc += A[m0..+64) @ Bp[n0..+192)^T, K=512, BK=32.
// 4 waves: wave w owns the 48-col triple (w*48) within the 192-col strip.
// (used by gru0_step only)
// ---------------------------------------------------------------------------
__device__ __forceinline__ void gru_mm(
    const __bf16* __restrict__ A, const __bf16* __restrict__ Bp,
    int m0, int n0, int tid, __bf16* As, __bf16* Bs, f32x4 (&acc)[4][3])
{
    const int lane = tid & 63, w = tid >> 6;
    const int u = lane & 15, koff = (lane >> 4) * 8;
    const __bf16* Ap  = A  + (size_t)(m0 + (tid >> 2)) * HID + (tid & 3) * 8;
    const __bf16* Bg0 = Bp + (size_t)(n0 + (tid >> 2)) * HID + (tid & 3) * 8;
    const __bf16* Bg1 = Bg0 + (size_t)64  * HID;
    const __bf16* Bg2 = Bg0 + (size_t)128 * HID;
    __bf16* AsW  = As + w * 512;
    __bf16* BsW0 = Bs + w * 512;
    __bf16* BsW1 = Bs + 2048 + w * 512;
    __bf16* BsW2 = Bs + 4096 + w * 512;

    for (int kt = 0; kt < HID / 32; ++kt) {
        __syncthreads();
        GLOAD_LDS16(Ap,  AsW);
        GLOAD_LDS16(Bg0, BsW0);
        GLOAD_LDS16(Bg1, BsW1);
        GLOAD_LDS16(Bg2, BsW2);
        Ap += 32; Bg0 += 32; Bg1 += 32; Bg2 += 32;
        __syncthreads();

        bf16x8 af[4], bfr[3];
        #pragma unroll
        for (int mf = 0; mf < 4; ++mf)
            af[mf] = *(const bf16x8*)&As[(mf * 16 + u) * 32 + koff];
        #pragma unroll
        for (int g = 0; g < 3; ++g)
            bfr[g] = *(const bf16x8*)&Bs[(w * 48 + g * 16 + u) * 32 + koff];
        #pragma unroll
        for (int mf = 0; mf < 4; ++mf)
            #pragma unroll
            for (int g = 0; g < 3; ++g)
                acc[mf][g] = __builtin_amdgcn_mfma_f32_16x16x32_bf16(
                    af[mf], bfr[g], acc[mf][g], 0, 0, 0);
    }
}

// ---------------------------------------------------------------------------
// K1: GRU0. gh0 = h0 @ whh0p^T; gi0 = G0p[p[row]] (b_ih0 folded);
// gate update -> h0_new (fp32 + bf16 mirror).
// ---------------------------------------------------------------------------
__global__ __launch_bounds__(256) void gru0_step(
    const __bf16* __restrict__ h0b_c, const __bf16* __restrict__ whh0p,
    const float* __restrict__ G0p, const int* __restrict__ p,
    const float* __restrict__ bhh0p,
    const float* __restrict__ h0f_c, float* __restrict__ h0f_n,
    __bf16* __restrict__ h0b_n)
{
    __shared__ __bf16 As[64 * 32];    // 4 KB
    __shared__ __bf16 Bs[192 * 32];   // 12 KB

    const int tid = threadIdx.x, lane = tid & 63, w = tid >> 6;
    const int u = lane & 15;
    const int m0 = blockIdx.x * 64;
    const int n0 = blockIdx.y * 192;
    const int t  = blockIdx.y * 4 + w;
    const int j  = t * 16 + u;
    const int qb = t * 48 + u;

    f32x4 acc[4][3] = {};
    gru_mm(h0b_c, whh0p, m0, n0, tid, As, Bs, acc);

    const float bhr = bhh0p[qb], bhz = bhh0p[qb + 16], bhn = bhh0p[qb + 32];
    const int rbase = m0 + ((lane >> 4) << 2);
    #pragma unroll
    for (int mf = 0; mf < 4; ++mf)
        #pragma unroll
        for (int r = 0; r < 4; ++r) {
            const int row = rbase + mf * 16 + r;
            const float* g0 = G0p + (size_t)p[row] * GATE3 + qb;
            const float rr = sig_(g0[0]  + acc[mf][0][r] + bhr);
            const float zz = sig_(g0[16] + acc[mf][1][r] + bhz);
            const float nn = tanh_(g0[32] + rr * (acc[mf][2][r] + bhn));
            const float hp = h0f_c[(size_t)row * HID + j];
            const float hv = (1.f - zz) * nn + zz * hp;
            h0f_n[(size_t)row * HID + j] = hv;
            h0b_n[(size_t)row * HID + j] = (__bf16)hv;
        }
}

// ---------------------------------------------------------------------------
// K2: GRU1 fused. gi1 = h0_new @ wih1p^T AND gh1 = h1 @ whh1p^T in ONE
// K-loop (both A tiles + both B strips staged per iter; 24 MFMA/phase,
// 8 in-flight gload_lds/thread). Barrier count halved vs dual loops.
// acc_i / acc_h stay separate (n-gate needs i_n and r*h_n separately).
// LDS 32 KB -> still >=3 blocks/CU.
// ---------------------------------------------------------------------------
__global__ __launch_bounds__(256) void gru1_fused(
    const __bf16* __restrict__ h0b_n, const __bf16* __restrict__ wih1p,
    const __bf16* __restrict__ h1b_c, const __bf16* __restrict__ whh1p,
    const float* __restrict__ bih1p, const float* __restrict__ bhh1p,
    const float* __restrict__ h1f_c, float* __restrict__ h1f_n,
    __bf16* __restrict__ h1b_n)
{
    __shared__ __bf16 Asi[64 * 32];    // 4 KB
    __shared__ __bf16 Ash[64 * 32];    // 4 KB
    __shared__ __bf16 Bsi[192 * 32];   // 12 KB
    __shared__ __bf16 Bsh[192 * 32];   // 12 KB

    const int tid = threadIdx.x, lane = tid & 63, w = tid >> 6;
    const int u = lane & 15, koff = (lane >> 4) * 8;
    const int m0 = blockIdx.x * 64;
    const int n0 = blockIdx.y * 192;
    const int t  = blockIdx.y * 4 + w;
    const int j  = t * 16 + u;
    const int qb = t * 48 + u;

    const __bf16* Api = h0b_n + (size_t)(m0 + (tid >> 2)) * HID + (tid & 3) * 8;
    const __bf16* Aph = h1b_c + (size_t)(m0 + (tid >> 2)) * HID + (tid & 3) * 8;
    const __bf16* Bi0 = wih1p + (size_t)(n0 + (tid >> 2)) * HID + (tid & 3) * 8;
    const __bf16* Bh0 = whh1p + (size_t)(n0 + (tid >> 2)) * HID + (tid & 3) * 8;
    const __bf16* Bi1 = Bi0 + (size_t)64  * HID;
    const __bf16* Bi2 = Bi0 + (size_t)128 * HID;
    const __bf16* Bh1 = Bh0 + (size_t)64  * HID;
    const __bf16* Bh2 = Bh0 + (size_t)128 * HID;

    __bf16* AsiW  = Asi + w * 512;
    __bf16* AshW  = Ash + w * 512;
    __bf16* BsiW0 = Bsi + w * 512;
    __bf16* BsiW1 = Bsi + 2048 + w * 512;
    __bf16* BsiW2 = Bsi + 4096 + w * 512;
    __bf16* BshW0 = Bsh + w * 512;
    __bf16* BshW1 = Bsh + 2048 + w * 512;
    __bf16* BshW2 = Bsh + 4096 + w * 512;

    f32x4 acc_i[4][3] = {};
    f32x4 acc_h[4][3] = {};

    for (int kt = 0; kt < HID / 32; ++kt) {
        __syncthreads();
        GLOAD_LDS16(Api, AsiW);
        GLOAD_LDS16(Aph, AshW);
        GLOAD_LDS16(Bi0, BsiW0);
        GLOAD_LDS16(Bi1, BsiW1);
        GLOAD_LDS16(Bi2, BsiW2);
        GLOAD_LDS16(Bh0, BshW0);
        GLOAD_LDS16(Bh1, BshW1);
        GLOAD_LDS16(Bh2, BshW2);
        Api += 32; Aph += 32;
        Bi0 += 32; Bi1 += 32; Bi2 += 32;
        Bh0 += 32; Bh1 += 32; Bh2 += 32;
        __syncthreads();

        bf16x8 bfi[3], bfh[3];
        #pragma unroll
        for (int g = 0; g < 3; ++g) {
            bfi[g] = *(const bf16x8*)&Bsi[(w * 48 + g * 16 + u) * 32 + koff];
            bfh[g] = *(const bf16x8*)&Bsh[(w * 48 + g * 16 + u) * 32 + koff];
        }
        #pragma unroll
        for (int mf = 0; mf < 4; ++mf) {
            const bf16x8 afi = *(const bf16x8*)&Asi[(mf * 16 + u) * 32 + koff];
            #pragma unroll
            for (int g = 0; g < 3; ++g)
                acc_i[mf][g] = __builtin_amdgcn_mfma_f32_16x16x32_bf16(
                    afi, bfi[g], acc_i[mf][g], 0, 0, 0);
            const bf16x8 afh = *(const bf16x8*)&Ash[(mf * 16 + u) * 32 + koff];
            #pragma unroll
            for (int g = 0; g < 3; ++g)
                acc_h[mf][g] = __builtin_amdgcn_mfma_f32_16x16x32_bf16(
                    afh, bfh[g], acc_h[mf][g], 0, 0, 0);
        }
    }

    const float bir = bih1p[qb], biz = bih1p[qb + 16], bin = bih1p[qb + 32];
    const float bhr = bhh1p[qb], bhz = bhh1p[qb + 16], bhn = bhh1p[qb + 32];
    const int rbase = m0 + ((lane >> 4) << 2);
    #pragma unroll
    for (int mf = 0; mf < 4; ++mf)
        #pragma unroll
        for (int r = 0; r < 4; ++r) {
            const int row = rbase + mf * 16 + r;
            const float rr = sig_(acc_i[mf][0][r] + bir + acc_h[mf][0][r] + bhr);
            const float zz = sig_(acc_i[mf][1][r] + biz + acc_h[mf][1][r] + bhz);
            const float nn = tanh_(acc_i[mf][2][r] + bin +
                                   rr * (acc_h[mf][2][r] + bhn));
            const float hp = h1f_c[(size_t)row * HID + j];
            const float hv = (1.f - zz) * nn + zz * hp;
            h1f_n[(size_t)row * HID + j] = hv;
            h1b_n[(size_t)row * HID + j] = (__bf16)hv;
        }
}

// ---------------------------------------------------------------------------
// K3: logits = h1_new @ w_out^T + b_out (MFMA, BM=32, N=64, K=512);
// log_softmax + argmax fused. 256 blocks x 128 threads (all CUs active);
// double-buffered LDS prefetch: stage(next) after barrier, compute(cur),
// one drain+barrier per iter -> load latency hidden under MFMA (this kernel
// has 1 block/CU, so no implicit multi-block overlap exists to rely on).
// wave w (0,1) -> rows m0 + w*16 ..; cols nf*16+u (all 64 per wave).
// ---------------------------------------------------------------------------
__global__ __launch_bounds__(128) void out_mfma(
    const __bf16* __restrict__ h1b, const __bf16* __restrict__ woutb,
    const float* __restrict__ bout, float* __restrict__ y, int* __restrict__ p)
{
    __shared__ __bf16 As[2 * 32 * 32];   // 2 x 2 KB
    __shared__ __bf16 Bs[2 * 64 * 32];   // 2 x 4 KB

    const int tid  = threadIdx.x;
    const int lane = tid & 63;
    const int w    = tid >> 6;            // 0..1
    const int m0   = blockIdx.x * 32;
    const int u    = lane & 15;
    const int koff = (lane >> 4) * 8;

    f32x4 acc[4] = {};

    // staging: A tile 32x32 (1 round), B tile 64x32 (2 rounds), 16B/thread.
    const __bf16* Ap  = h1b   + (size_t)(m0 + (tid >> 2)) * HID + (tid & 3) * 8;
    const __bf16* Wp0 = woutb + (size_t)(tid >> 2) * HID + (tid & 3) * 8;
    const __bf16* Wp1 = Wp0 + (size_t)32 * HID;

    // prologue: fill buffer 0
    GLOAD_LDS16(Ap,  As + w * 512);
    GLOAD_LDS16(Wp0, Bs + w * 512);
    GLOAD_LDS16(Wp1, Bs + 1024 + w * 512);
    Ap += 32; Wp0 += 32; Wp1 += 32;
    __syncthreads();   // implies vmcnt(0) drain

    #pragma unroll
    for (int kt = 0; kt < HID / 32; ++kt) {
        const int cur = kt & 1, nxt = cur ^ 1;
        if (kt < HID / 32 - 1) {
            GLOAD_LDS16(Ap,  As + nxt * 1024 + w * 512);
            GLOAD_LDS16(Wp0, Bs + nxt * 2048 + w * 512);
            GLOAD_LDS16(Wp1, Bs + nxt * 2048 + 1024 + w * 512);
            Ap += 32; Wp0 += 32; Wp1 += 32;
        }
        const bf16x8 af = *(const bf16x8*)&As[cur * 1024 + (w * 16 + u) * 32 + koff];
        #pragma unroll
        for (int nf = 0; nf < 4; ++nf) {
            const bf16x8 bfr = *(const bf16x8*)&Bs[cur * 2048 + (nf * 16 + u) * 32 + koff];
            acc[nf] = __builtin_amdgcn_mfma_f32_16x16x32_bf16(af, bfr, acc[nf], 0, 0, 0);
        }
        __syncthreads();   // drains the prefetch into nxt; buffers flip
    }

    #pragma unroll
    for (int r = 0; r < 4; ++r) {
        const int row = m0 + w * 16 + ((lane >> 4) << 2) + r;
        float l[4];
        #pragma unroll
        for (int nf = 0; nf < 4; ++nf) l[nf] = acc[nf][r] + bout[nf * 16 + u];

        float mv = l[0]; int mi = u;
        #pragma unroll
        for (int nf = 1; nf < 4; ++nf)
            if (l[nf] > mv) { mv = l[nf]; mi = nf * 16 + u; }
        #pragma unroll
        for (int off = 1; off <= 8; off <<= 1) {
            const float ov = __shfl_xor(mv, off, 64);
            const int   oi = __shfl_xor(mi, off, 64);
            if (ov > mv || (ov == mv && oi < mi)) { mv = ov; mi = oi; }
        }
        float se = 0.f;
        #pragma unroll
        for (int nf = 0; nf < 4; ++nf) se += __expf(l[nf] - mv);
        #pragma unroll
        for (int off = 1; off <= 8; off <<= 1) se += __shfl_xor(se, off, 64);
        const float lse = logf(se);

        #pragma unroll
        for (int nf = 0; nf < 4; ++nf)
            y[(size_t)row * ATOM + nf * 16 + u] = l[nf] - mv - lse;
        if (u == 0) p[row] = mi;
    }
}

// ---------------------------------------------------------------------------
// Init GEMM (enc -> h): 128x128 tile, LDS-staged, tanh epilogue split h0|h1.
// ---------------------------------------------------------------------------
__global__ __launch_bounds__(256) void gemm_init(
    const __bf16* __restrict__ A, const __bf16* __restrict__ B,
    int N, int K, const float* __restrict__ bias,
    float* __restrict__ H0f, __bf16* __restrict__ H0b,
    float* __restrict__ H1f, __bf16* __restrict__ H1b)
{
    __shared__ __bf16 As[128 * 32];
    __shared__ __bf16 Bs[128 * 32];

    const int tid  = threadIdx.x;
    const int lane = tid & 63;
    const int w    = tid >> 6;
    const int wm   = w >> 1, wn = w & 1;
    const int m0   = blockIdx.x * 128;
    const int n0   = blockIdx.y * 128;

    f32x4 acc[4][4] = {};

    const int i0 = w * 64 + lane;
    const int i1 = i0 + 256;
    const __bf16* Ap0 = A + (size_t)(m0 + (i0 >> 2)) * K + (i0 & 3) * 8;
    const __bf16* Ap1 = A + (size_t)(m0 + (i1 >> 2)) * K + (i1 & 3) * 8;
    const __bf16* Bp0 = B + (size_t)(n0 + (i0 >> 2)) * K + (i0 & 3) * 8;
    const __bf16* Bp1 = B + (size_t)(n0 + (i1 >> 2)) * K + (i1 & 3) * 8;
    __bf16* As0 = As + w * 512;
    __bf16* As1 = As + 2048 + w * 512;
    __bf16* Bs0 = Bs + w * 512;
    __bf16* Bs1 = Bs + 2048 + w * 512;

    const int mrow = wm * 64 + (lane & 15);
    const int nrow = wn * 64 + (lane & 15);
    const int koff = (lane >> 4) * 8;

    for (int kt = 0; kt < K / 32; ++kt) {
        __syncthreads();
        GLOAD_LDS16(Ap0, As0);
        GLOAD_LDS16(Ap1, As1);
        GLOAD_LDS16(Bp0, Bs0);
        GLOAD_LDS16(Bp1, Bs1);
        Ap0 += 32; Ap1 += 32; Bp0 += 32; Bp1 += 32;
        __syncthreads();

        bf16x8 af[4], bfr[4];
        #pragma unroll
        for (int f = 0; f < 4; ++f) {
            af[f]  = *(const bf16x8*)&As[(mrow + f * 16) * 32 + koff];
            bfr[f] = *(const bf16x8*)&Bs[(nrow + f * 16) * 32 + koff];
        }
        #pragma unroll
        for (int mf = 0; mf < 4; ++mf)
            #pragma unroll
            for (int nf = 0; nf < 4; ++nf)
                acc[mf][nf] = __builtin_amdgcn_mfma_f32_16x16x32_bf16(
                    af[mf], bfr[nf], acc[mf][nf], 0, 0, 0);
    }

    const int colb = n0 + wn * 64 + (lane & 15);
    const int rowb = m0 + wm * 64 + ((lane >> 4) << 2);
    #pragma unroll
    for (int mf = 0; mf < 4; ++mf)
        #pragma unroll
        for (int nf = 0; nf < 4; ++nf) {
            const int col = colb + nf * 16;
            #pragma unroll
            for (int r = 0; r < 4; ++r) {
                const int row = rowb + mf * 16 + r;
                const float v = tanhf(acc[mf][nf][r] + bias[col]);
                if (col < HID) {
                    H0f[(size_t)row * HID + col] = v;
                    H0b[(size_t)row * HID + col] = (__bf16)v;
                } else {
                    H1f[(size_t)row * HID + col - HID] = v;
                    H1b[(size_t)row * HID + col - HID] = (__bf16)v;
                }
            }
        }
}

// ---------------------------------------------------------------------------
// prep kernels
// ---------------------------------------------------------------------------
__device__ inline int permQ(int q) {          // permuted q -> original row
    const int t = q / 48, rem = q % 48;
    return (rem / 16) * HID + t * 16 + (rem % 16);
}

__global__ __launch_bounds__(256) void f2b(const float* __restrict__ s,
                                           __bf16* __restrict__ d, int n)
{
    const int i = (blockIdx.x * 256 + threadIdx.x) * 4;
    if (i + 3 < n) {
        const float4 v = *(const float4*)(s + i);
        bf16x4 o = { (__bf16)v.x, (__bf16)v.y, (__bf16)v.z, (__bf16)v.w };
        *(bf16x4*)(d + i) = o;
    }
}

__global__ __launch_bounds__(256) void f2bp(const float* __restrict__ s,
                                            __bf16* __restrict__ d)
{
    const int idx = blockIdx.x * 256 + threadIdx.x;   // 1536*128
    const int q = idx >> 7, k = (idx & 127) << 2;
    const int o = permQ(q);
    const float4 v = *(const float4*)(s + (size_t)o * HID + k);
    bf16x4 ov = { (__bf16)v.x, (__bf16)v.y, (__bf16)v.z, (__bf16)v.w };
    *(bf16x4*)(d + (size_t)q * HID + k) = ov;
}

__global__ __launch_bounds__(256) void bperm(const float* __restrict__ s,
                                             float* __restrict__ d)
{
    const int q = blockIdx.x * 256 + threadIdx.x;
    if (q < GATE3) d[q] = s[permQ(q)];
}

__global__ __launch_bounds__(256) void g0pk(const float* __restrict__ emb,
                                            const float* __restrict__ wih0,
                                            const float* __restrict__ bih0,
                                            float* __restrict__ G0p)
{
    const int i = blockIdx.x * 256 + threadIdx.x;   // 64*1536
    if (i >= ATOM * GATE3) return;
    const int a = i / GATE3, q = i % GATE3;
    const int o = permQ(q);
    float s = bih0[o];
    for (int k = 0; k < 50; ++k) s += emb[a * 50 + k] * wih0[o * 50 + k];
    G0p[i] = s;
}

__global__ __launch_bounds__(256) void initp(int* __restrict__ p)
{
    const int i = blockIdx.x * 256 + threadIdx.x;
    if (i < B_ROWS) p[i] = 1;   // SOS
}

// ---------------------------------------------------------------------------
extern "C" void kernel_launch(void* const* d_in, const int* in_sizes, int n_in,
                              void* d_out, int out_size, void* d_ws, size_t ws_size,
                              hipStream_t stream)
{
    (void)in_sizes; (void)n_in; (void)out_size; (void)ws_size;
    const float* enc   = (const float*)d_in[0];
    const float* emb   = (const float*)d_in[1];
    const float* w_h0  = (const float*)d_in[2];
    const float* b_h0  = (const float*)d_in[3];
    const float* w_ih0 = (const float*)d_in[4];
    const float* w_hh0 = (const float*)d_in[5];
    const float* b_ih0 = (const float*)d_in[6];
    const float* b_hh0 = (const float*)d_in[7];
    const float* w_ih1 = (const float*)d_in[8];
    const float* w_hh1 = (const float*)d_in[9];
    const float* b_ih1 = (const float*)d_in[10];
    const float* b_hh1 = (const float*)d_in[11];
    const float* w_out = (const float*)d_in[12];
    const float* b_out = (const float*)d_in[13];
    float* out = (float*)d_out;

    char* ws = (char*)d_ws;
    size_t off = 0;
    auto alloc = [&](size_t bytes) -> void* {
        void* pp = ws + off;
        off = (off + bytes + 255) & ~(size_t)255;
        return pp;
    };
    __bf16* whh0p = (__bf16*)alloc((size_t)GATE3 * HID * 2);
    __bf16* wih1p = (__bf16*)alloc((size_t)GATE3 * HID * 2);
    __bf16* whh1p = (__bf16*)alloc((size_t)GATE3 * HID * 2);
    __bf16* woutb = (__bf16*)alloc((size_t)ATOM * HID * 2);
    float*  G0p   = (float*) alloc((size_t)ATOM * GATE3 * 4);
    float*  bhh0p = (float*) alloc(GATE3 * 4);
    float*  bih1p = (float*) alloc(GATE3 * 4);
    float*  bhh1p = (float*) alloc(GATE3 * 4);
    float*  h0f[2]; __bf16* h0b[2]; float* h1f[2]; __bf16* h1b[2];
    for (int i = 0; i < 2; ++i) {
        h0f[i] = (float*) alloc((size_t)B_ROWS * HID * 4);
        h0b[i] = (__bf16*)alloc((size_t)B_ROWS * HID * 2);
        h1f[i] = (float*) alloc((size_t)B_ROWS * HID * 4);
        h1b[i] = (__bf16*)alloc((size_t)B_ROWS * HID * 2);
    }
    int* p = (int*)alloc((size_t)B_ROWS * 4);
    __bf16* enc_b = (__bf16*)alloc((size_t)B_ROWS * 1024 * 2);
    __bf16* wh0b  = (__bf16*)alloc((size_t)1024 * 1024 * 2);

    // ---- prep ----
    f2b <<<8192, 256, 0, stream>>>(enc,  enc_b, B_ROWS * 1024);
    f2b <<<1024, 256, 0, stream>>>(w_h0, wh0b,  1024 * 1024);
    f2b <<<32,   256, 0, stream>>>(w_out, woutb, ATOM * HID);
    f2bp<<<768,  256, 0, stream>>>(w_hh0, whh0p);
    f2bp<<<768,  256, 0, stream>>>(w_ih1, wih1p);
    f2bp<<<768,  256, 0, stream>>>(w_hh1, whh1p);
    bperm<<<6, 256, 0, stream>>>(b_hh0, bhh0p);
    bperm<<<6, 256, 0, stream>>>(b_ih1, bih1p);
    bperm<<<6, 256, 0, stream>>>(b_hh1, bhh1p);
    g0pk<<<384, 256, 0, stream>>>(emb, w_ih0, b_ih0, G0p);
    initp<<<32, 256, 0, stream>>>(p);

    gemm_init<<<dim3(B_ROWS / 128, 1024 / 128), 256, 0, stream>>>(
        enc_b, wh0b, 1024, 1024, b_h0, h0f[0], h0b[0], h1f[0], h1b[0]);

    // ---- 49 decode steps: 3 launches each ----
    const dim3 gGrid(B_ROWS / 64, GATE3 / 192);   // m-tile fastest (XCD locality)
    for (int step = 0; step < NSTEP; ++step) {
        const int cur = step & 1, nxt = cur ^ 1;
        gru0_step<<<gGrid, 256, 0, stream>>>(
            h0b[cur], whh0p, G0p, p, bhh0p, h0f[cur], h0f[nxt], h0b[nxt]);
        gru1_fused<<<gGrid, 256, 0, stream>>>(
            h0b[nxt], wih1p, h1b[cur], whh1p, bih1p, bhh1p,
            h1f[cur], h1f[nxt], h1b[nxt]);
        out_mfma<<<B_ROWS / 32, 128, 0, stream>>>(
            h1b[nxt], woutb, b_out, out + (size_t)step * B_ROWS * ATOM, p);
    }
}